// Round 2
// baseline (251.258 us; speedup 1.0000x reference)
//
#include <hip/hip_runtime.h>

#define NROWS 4096
#define TLEN  2048
#define BLOCK 256
#define PER_THREAD 8   // TLEN / BLOCK
#define LAMBDA 0.95f

__device__ __forceinline__ void load8f(const float* __restrict__ p, float* d) {
    float4 a = ((const float4*)p)[0];
    float4 b = ((const float4*)p)[1];
    d[0]=a.x; d[1]=a.y; d[2]=a.z; d[3]=a.w;
    d[4]=b.x; d[5]=b.y; d[6]=b.z; d[7]=b.w;
}

__global__ __launch_bounds__(BLOCK) void retrace_loss_kernel(
    const float* __restrict__ current_qf,
    const float* __restrict__ target_qf_tp1,
    const float* __restrict__ target_q_tp1,
    const float* __restrict__ rewards,
    const float* __restrict__ pcont,
    const float* __restrict__ logpacs,
    const float* __restrict__ old_logpacs,
    const float* __restrict__ entropy_p,
    const int*   __restrict__ timeout,
    float* __restrict__ partials)            // [NROWS] block partial sums
{
    const int row  = blockIdx.x;
    const int tid  = threadIdx.x;
    const int lane = tid & 63;
    const int wave = tid >> 6;
    const int base = row * TLEN + tid * PER_THREAD;

    const float ent = entropy_p[0];

    // ---- vector loads (coalesced, 32B/thread/array) ----
    float tqf[PER_THREAD], tv[PER_THREAD], rw[PER_THREAD], pc[PER_THREAD];
    float lp[PER_THREAD], olp[PER_THREAD];
    load8f(target_qf_tp1 + base, tqf);
    load8f(target_q_tp1  + base, tv);
    load8f(rewards       + base, rw);
    load8f(pcont         + base, pc);
    load8f(logpacs       + base, lp);
    load8f(old_logpacs   + base, olp);
    int4 ti0 = ((const int4*)(timeout + base))[0];
    int4 ti1 = ((const int4*)(timeout + base))[1];
    int to[PER_THREAD] = {ti0.x, ti0.y, ti0.z, ti0.w, ti1.x, ti1.y, ti1.z, ti1.w};

    // ---- per-element affine coefficients: q[t] = a[t] + b[t]*q[t+1] ----
    float aco[PER_THREAD], bco[PER_THREAD];
    #pragma unroll
    for (int j = 0; j < PER_THREAD; ++j) {
        float m  = to[j] ? 0.0f : 1.0f;
        float c  = LAMBDA * __expf(fminf(lp[j] - olp[j], 0.0f));
        float mc = m * c;
        bco[j] = pc[j] * mc;
        aco[j] = rw[j] + pc[j] * (tv[j] + ent - mc * tqf[j]);
    }
    // terminal: q[T-1] = target_qf_tp1[:, -1]  (b=0 kills any carry)
    if (tid == BLOCK - 1) { aco[PER_THREAD-1] = tqf[PER_THREAD-1]; bco[PER_THREAD-1] = 0.0f; }

    // ---- per-thread chunk composition (right-to-left): q[lo] = A + B*carry ----
    float A = aco[PER_THREAD-1], Bc = bco[PER_THREAD-1];
    #pragma unroll
    for (int j = PER_THREAD - 2; j >= 0; --j) { A = aco[j] + bco[j] * A; Bc = bco[j] * Bc; }

    // ---- wave-level inclusive suffix scan of affine pairs (Hillis-Steele) ----
    float sA = A, sB = Bc;
    #pragma unroll
    for (int off = 1; off < 64; off <<= 1) {
        float nA = __shfl_down(sA, off);
        float nB = __shfl_down(sB, off);
        if (lane + off < 64) { sA = sA + sB * nA; sB = sB * nB; }
    }
    // exclusive suffix within wave: lane i gets inclusive of lane i+1; lane 63 = identity
    float eA = __shfl_down(sA, 1);
    float eB = __shfl_down(sB, 1);
    if (lane == 63) { eA = 0.0f; eB = 1.0f; }

    // ---- wave carries via LDS (4 waves) ----
    __shared__ float wA[4], wB[4], psum[4];
    if (lane == 0) { wA[wave] = sA; wB[wave] = sB; }  // inclusive at lane 0 = whole-wave comp
    __syncthreads();
    float gA = 0.0f, gB = 1.0f;               // compose waves to the right of this wave
    for (int j = wave + 1; j < 4; ++j) { gA = gA + gB * wA[j]; gB = gB * wB[j]; }

    // carry into this thread's chunk (seed irrelevant: composed B through tail is 0)
    float carry = eA + eB * gA;

    // ---- replay chunk sequentially (matches reference fp32 order), MSE accumulate ----
    float cq[PER_THREAD];
    load8f(current_qf + base, cq);
    float q = carry;
    float sum = 0.0f;
    #pragma unroll
    for (int j = PER_THREAD - 1; j >= 0; --j) {
        q = aco[j] + bco[j] * q;              // q_ret[t = base+j]
        float d = cq[j] - q;
        sum += d * d;
    }

    // ---- block reduction -> ONE uncontended store per block (no atomics) ----
    #pragma unroll
    for (int off = 32; off > 0; off >>= 1) sum += __shfl_down(sum, off);
    if (lane == 0) psum[wave] = sum;
    __syncthreads();
    if (tid == 0) {
        partials[row] = psum[0] + psum[1] + psum[2] + psum[3];
    }
}

// reduce 4096 partials -> mean; single block, no atomics
__global__ __launch_bounds__(BLOCK) void reduce_kernel(
    const float* __restrict__ partials, float* __restrict__ out)
{
    const int tid  = threadIdx.x;
    const int lane = tid & 63;
    const int wave = tid >> 6;
    float sum = 0.0f;
    #pragma unroll
    for (int k = 0; k < NROWS / BLOCK / 4; ++k) {           // 4 float4 per thread
        float4 v = ((const float4*)partials)[tid + k * BLOCK];
        sum += v.x + v.y + v.z + v.w;
    }
    #pragma unroll
    for (int off = 32; off > 0; off >>= 1) sum += __shfl_down(sum, off);
    __shared__ float psum[4];
    if (lane == 0) psum[wave] = sum;
    __syncthreads();
    if (tid == 0) {
        float s = psum[0] + psum[1] + psum[2] + psum[3];
        out[0] = s * (1.0f / ((float)NROWS * (float)TLEN));
    }
}

extern "C" void kernel_launch(void* const* d_in, const int* in_sizes, int n_in,
                              void* d_out, int out_size, void* d_ws, size_t ws_size,
                              hipStream_t stream) {
    const float* current_qf     = (const float*)d_in[0];
    const float* target_qf_tp1  = (const float*)d_in[1];
    const float* target_q_tp1   = (const float*)d_in[2];
    const float* rewards        = (const float*)d_in[3];
    const float* pcont          = (const float*)d_in[4];
    const float* logpacs        = (const float*)d_in[5];
    const float* old_logpacs    = (const float*)d_in[6];
    const float* entropy        = (const float*)d_in[7];
    const int*   timeout        = (const int*)d_in[8];
    float* partials = (float*)d_ws;          // 4096 floats = 16 KB scratch
    float* out = (float*)d_out;

    retrace_loss_kernel<<<NROWS, BLOCK, 0, stream>>>(
        current_qf, target_qf_tp1, target_q_tp1, rewards, pcont,
        logpacs, old_logpacs, entropy, timeout, partials);
    reduce_kernel<<<1, BLOCK, 0, stream>>>(partials, out);
}

// Round 3
// 250.810 us; speedup vs baseline: 1.0018x; 1.0018x over previous
//
#include <hip/hip_runtime.h>

#define NROWS 4096
#define TLEN  2048
#define BLOCK 256
#define PER_THREAD 8   // TLEN / BLOCK
#define LAMBDA 0.95f

__global__ __launch_bounds__(BLOCK, 4) void retrace_loss_kernel(
    const float* __restrict__ current_qf,
    const float* __restrict__ target_qf_tp1,
    const float* __restrict__ target_q_tp1,
    const float* __restrict__ rewards,
    const float* __restrict__ pcont,
    const float* __restrict__ logpacs,
    const float* __restrict__ old_logpacs,
    const float* __restrict__ entropy_p,
    const int*   __restrict__ timeout,
    float* __restrict__ partials)            // [NROWS] block partial sums
{
    const int row  = blockIdx.x;
    const int tid  = threadIdx.x;
    const int lane = tid & 63;
    const int wave = tid >> 6;
    const int base = row * TLEN + tid * PER_THREAD;

    // ---- issue ALL global loads back-to-back (16x16B fp32 + 2x16B int) ----
    // Keep results in float4 temporaries so no dependent code intervenes:
    // maximizes outstanding vmem requests per wave (MLP), the R2 bottleneck.
    const float4* pq  = (const float4*)(current_qf    + base);
    const float4* ptq = (const float4*)(target_qf_tp1 + base);
    const float4* ptv = (const float4*)(target_q_tp1  + base);
    const float4* prw = (const float4*)(rewards       + base);
    const float4* ppc = (const float4*)(pcont         + base);
    const float4* plp = (const float4*)(logpacs       + base);
    const float4* pol = (const float4*)(old_logpacs   + base);
    const int4*   pto = (const int4*)  (timeout       + base);

    float4 vq0  = pq[0],  vq1  = pq[1];
    float4 vtq0 = ptq[0], vtq1 = ptq[1];
    float4 vtv0 = ptv[0], vtv1 = ptv[1];
    float4 vrw0 = prw[0], vrw1 = prw[1];
    float4 vpc0 = ppc[0], vpc1 = ppc[1];
    float4 vlp0 = plp[0], vlp1 = plp[1];
    float4 vol0 = pol[0], vol1 = pol[1];
    int4   vto0 = pto[0], vto1 = pto[1];
    const float ent = entropy_p[0];

    float cq[PER_THREAD]  = {vq0.x,vq0.y,vq0.z,vq0.w,vq1.x,vq1.y,vq1.z,vq1.w};
    float tqf[PER_THREAD] = {vtq0.x,vtq0.y,vtq0.z,vtq0.w,vtq1.x,vtq1.y,vtq1.z,vtq1.w};
    float tv[PER_THREAD]  = {vtv0.x,vtv0.y,vtv0.z,vtv0.w,vtv1.x,vtv1.y,vtv1.z,vtv1.w};
    float rw[PER_THREAD]  = {vrw0.x,vrw0.y,vrw0.z,vrw0.w,vrw1.x,vrw1.y,vrw1.z,vrw1.w};
    float pc[PER_THREAD]  = {vpc0.x,vpc0.y,vpc0.z,vpc0.w,vpc1.x,vpc1.y,vpc1.z,vpc1.w};
    float lp[PER_THREAD]  = {vlp0.x,vlp0.y,vlp0.z,vlp0.w,vlp1.x,vlp1.y,vlp1.z,vlp1.w};
    float olp[PER_THREAD] = {vol0.x,vol0.y,vol0.z,vol0.w,vol1.x,vol1.y,vol1.z,vol1.w};
    int   to[PER_THREAD]  = {vto0.x,vto0.y,vto0.z,vto0.w,vto1.x,vto1.y,vto1.z,vto1.w};

    // ---- per-element affine coefficients: q[t] = a[t] + b[t]*q[t+1] ----
    float aco[PER_THREAD], bco[PER_THREAD];
    #pragma unroll
    for (int j = 0; j < PER_THREAD; ++j) {
        float m  = to[j] ? 0.0f : 1.0f;
        float c  = LAMBDA * __expf(fminf(lp[j] - olp[j], 0.0f));
        float mc = m * c;
        bco[j] = pc[j] * mc;
        aco[j] = rw[j] + pc[j] * (tv[j] + ent - mc * tqf[j]);
    }
    // terminal: q[T-1] = target_qf_tp1[:, -1]  (b=0 kills any carry)
    if (tid == BLOCK - 1) { aco[PER_THREAD-1] = tqf[PER_THREAD-1]; bco[PER_THREAD-1] = 0.0f; }

    // ---- per-thread chunk composition (right-to-left): q[lo] = A + B*carry ----
    float A = aco[PER_THREAD-1], Bc = bco[PER_THREAD-1];
    #pragma unroll
    for (int j = PER_THREAD - 2; j >= 0; --j) { A = aco[j] + bco[j] * A; Bc = bco[j] * Bc; }

    // ---- wave-level inclusive suffix scan of affine pairs (Hillis-Steele) ----
    float sA = A, sB = Bc;
    #pragma unroll
    for (int off = 1; off < 64; off <<= 1) {
        float nA = __shfl_down(sA, off);
        float nB = __shfl_down(sB, off);
        if (lane + off < 64) { sA = sA + sB * nA; sB = sB * nB; }
    }
    // exclusive suffix within wave: lane i gets inclusive of lane i+1; lane 63 = identity
    float eA = __shfl_down(sA, 1);
    float eB = __shfl_down(sB, 1);
    if (lane == 63) { eA = 0.0f; eB = 1.0f; }

    // ---- wave carries via LDS (4 waves) ----
    __shared__ float wA[4], wB[4], psum[4];
    if (lane == 0) { wA[wave] = sA; wB[wave] = sB; }  // inclusive at lane 0 = whole-wave comp
    __syncthreads();
    float gA = 0.0f, gB = 1.0f;               // compose waves to the right of this wave
    for (int j = wave + 1; j < 4; ++j) { gA = gA + gB * wA[j]; gB = gB * wB[j]; }

    // carry into this thread's chunk (seed irrelevant: composed B through tail is 0)
    float carry = eA + eB * gA;

    // ---- replay chunk sequentially (matches reference fp32 order), MSE accumulate ----
    float q = carry;
    float sum = 0.0f;
    #pragma unroll
    for (int j = PER_THREAD - 1; j >= 0; --j) {
        q = aco[j] + bco[j] * q;              // q_ret[t = base+j]
        float d = cq[j] - q;
        sum += d * d;
    }

    // ---- block reduction -> ONE uncontended store per block (no atomics) ----
    #pragma unroll
    for (int off = 32; off > 0; off >>= 1) sum += __shfl_down(sum, off);
    if (lane == 0) psum[wave] = sum;
    __syncthreads();
    if (tid == 0) {
        partials[row] = psum[0] + psum[1] + psum[2] + psum[3];
    }
}

// reduce 4096 partials -> mean; single block, no atomics
__global__ __launch_bounds__(BLOCK) void reduce_kernel(
    const float* __restrict__ partials, float* __restrict__ out)
{
    const int tid  = threadIdx.x;
    const int lane = tid & 63;
    const int wave = tid >> 6;
    float sum = 0.0f;
    #pragma unroll
    for (int k = 0; k < NROWS / BLOCK / 4; ++k) {           // 4 float4 per thread
        float4 v = ((const float4*)partials)[tid + k * BLOCK];
        sum += v.x + v.y + v.z + v.w;
    }
    #pragma unroll
    for (int off = 32; off > 0; off >>= 1) sum += __shfl_down(sum, off);
    __shared__ float psum[4];
    if (lane == 0) psum[wave] = sum;
    __syncthreads();
    if (tid == 0) {
        float s = psum[0] + psum[1] + psum[2] + psum[3];
        out[0] = s * (1.0f / ((float)NROWS * (float)TLEN));
    }
}

extern "C" void kernel_launch(void* const* d_in, const int* in_sizes, int n_in,
                              void* d_out, int out_size, void* d_ws, size_t ws_size,
                              hipStream_t stream) {
    const float* current_qf     = (const float*)d_in[0];
    const float* target_qf_tp1  = (const float*)d_in[1];
    const float* target_q_tp1   = (const float*)d_in[2];
    const float* rewards        = (const float*)d_in[3];
    const float* pcont          = (const float*)d_in[4];
    const float* logpacs        = (const float*)d_in[5];
    const float* old_logpacs    = (const float*)d_in[6];
    const float* entropy        = (const float*)d_in[7];
    const int*   timeout        = (const int*)d_in[8];
    float* partials = (float*)d_ws;          // 4096 floats = 16 KB scratch
    float* out = (float*)d_out;

    retrace_loss_kernel<<<NROWS, BLOCK, 0, stream>>>(
        current_qf, target_qf_tp1, target_q_tp1, rewards, pcont,
        logpacs, old_logpacs, entropy, timeout, partials);
    reduce_kernel<<<1, BLOCK, 0, stream>>>(partials, out);
}